// Round 6
// baseline (263.987 us; speedup 1.0000x reference)
//
#include <hip/hip_runtime.h>

// Two-pass 3x3 VALID conv:
//  pass 1: pack x fp32 [16][2048][2048] -> xt bf16 [h][w][16ci] in d_ws
//          (ci-half 16B chunks swapped when (w&4) — pre-swizzle for LDS reads);
//          block 0 also precomputes per-lane MFMA weight fragments -> d_ws.
//  pass 2: strip-persistent implicit-GEMM conv, 2-phase double-buffered LDS:
//          per block, 8 w-tiles; stage tile t+1 via global_load_lds while
//          computing tile t; counted s_waitcnt vmcnt(8) + raw s_barrier
//          (stage loads are the oldest VMEM ops; 8 stores follow).

#define HIN   2048
#define WIN   2048
#define HOUT  2046
#define WOUT  2046
#define PLANE_IN  (HIN * WIN)
#define PLANE_OUT (HOUT * WOUT)
#define TR 34
#define TC 34
#define NCHUNK (TR * TC * 2)           // 2312 16B-chunks per tile
#define BUFU32 (NCHUNK * 4)            // 9248 u32 = 36992 B per buffer
#define STRIP 8
#define XT_U32 ((size_t)HIN * WIN * 8) // xt size in u32
#define WF_U32 (5 * 64 * 4)            // weight-frag buffer in u32 (5 KiB)

typedef __attribute__((ext_vector_type(8))) short bf16x8;
typedef __attribute__((ext_vector_type(4))) float f32x4;
typedef __attribute__((ext_vector_type(4))) unsigned u32x4;
typedef f32x4 __attribute__((aligned(4))) f32x4_u;

static __device__ __forceinline__ short f2bf(float f) {
    unsigned u = __float_as_uint(f);
    return (short)((u + 0x7FFFu + ((u >> 16) & 1u)) >> 16);   // RNE
}
static __device__ __forceinline__ unsigned pk2(float lo, float hi) {
    unsigned a = __float_as_uint(lo);
    unsigned b = __float_as_uint(hi);
    a = (a + 0x7FFFu + ((a >> 16) & 1u)) >> 16;
    b = (b + 0x7FFFu + ((b >> 16) & 1u)) & 0xFFFF0000u;
    return a | b;
}

// ---------------- pass 1: pack/transpose/convert (+ weight fragments) --------
__global__ __launch_bounds__(256, 4)
void pack_bf16(const float* __restrict__ x, const float* __restrict__ k,
               unsigned* __restrict__ xt, unsigned* __restrict__ wfbuf) {
    if (blockIdx.x == 0 && threadIdx.x < 64) {
        int lane = threadIdx.x;
        int m = lane & 15, g = lane >> 4;
        #pragma unroll
        for (int i = 0; i < 5; ++i) {
            u32x4 q;
            #pragma unroll
            for (int jj = 0; jj < 4; ++jj) {
                unsigned r = 0;
                #pragma unroll
                for (int e = 0; e < 2; ++e) {
                    int kk  = 32 * i + 8 * g + 2 * jj + e;
                    int tap = kk >> 4;
                    int ci  = kk & 15;
                    unsigned v = 0;
                    if (tap < 9) v = (unsigned short)f2bf(k[(m * 16 + ci) * 9 + tap]);
                    r |= v << (16 * e);
                }
                q[jj] = r;
            }
            *(u32x4*)(wfbuf + (i * 64 + lane) * 4) = q;
        }
    }

    int id = blockIdx.x * 256 + threadIdx.x;   // 2048 rows x 1024 pairs
    int h  = id >> 10;
    int w0 = (id & 1023) << 1;
    const float* gp = x + h * WIN + w0;
    float2 v[16];
    #pragma unroll
    for (int ci = 0; ci < 16; ++ci) v[ci] = *(const float2*)(gp + ci * PLANE_IN);

    u32x4 lo0, hi0, lo1, hi1;
    #pragma unroll
    for (int p = 0; p < 4; ++p) {
        lo0[p] = pk2(v[2 * p].x,     v[2 * p + 1].x);
        hi0[p] = pk2(v[2 * p + 8].x, v[2 * p + 9].x);
        lo1[p] = pk2(v[2 * p].y,     v[2 * p + 1].y);
        hi1[p] = pk2(v[2 * p + 8].y, v[2 * p + 9].y);
    }
    int sw = (w0 & 4) ? 4 : 0;
    unsigned* op = xt + (h * WIN + w0) * 8;
    *(u32x4*)(op + sw)           = lo0;
    *(u32x4*)(op + (4 - sw))     = hi0;
    *(u32x4*)(op + 8 + sw)       = lo1;
    *(u32x4*)(op + 8 + (4 - sw)) = hi1;
}

// ---------------- pass 2: strip-persistent 2-phase MFMA conv ----------------
__global__ __launch_bounds__(512, 4)
void conv3x3_strip(const unsigned* __restrict__ xt,
                   const unsigned* __restrict__ wfbuf,
                   float* __restrict__ out) {
    extern __shared__ unsigned lds[];      // 2 * 36992 B

    const int tid  = threadIdx.x;
    const int lane = tid & 63;
    const int wv   = tid >> 6;
    const int m    = lane & 15;
    const int g    = lane >> 4;

    int bid   = blockIdx.x;                    // 512 blocks (64 hb x 8 strips)
    int swz   = (bid & 7) * 64 + (bid >> 3);   // XCD-chunked (512 % 8 == 0)
    int hb    = swz >> 3;
    int strip = swz & 7;
    int h0 = hb * 32; if (h0 > HOUT - 32) h0 = HOUT - 32;   // 2014
    int w0base = strip * 256;

    // per-thread stage decomposition: 4 main chunks + optional tail chunk
    const unsigned* sbase[5];
    int swloc[5];
    int sdst[5];
    #pragma unroll
    for (int p = 0; p < 5; ++p) {
        int c   = (p < 4) ? (p * 512 + tid) : (2048 + tid);
        int row = (c * 964) >> 16;             // c/68, exact for c<2312
        int sub = c - row * 68;
        sbase[p] = xt + (size_t)(h0 + row) * (WIN * 8) + (sub & 1) * 4;
        swloc[p] = sub >> 1;
        sdst[p]  = ((p < 4) ? (p * 512 + wv * 64) : (2048 + wv * 64)) * 4;
    }
    const bool tail = (tid < 264);

    // weight fragments: 5 coalesced 16B loads
    bf16x8 wf[5];
    #pragma unroll
    for (int i = 0; i < 5; ++i)
        wf[i] = *(const bf16x8*)(wfbuf + (i * 64 + lane) * 4);

    // per-lane A-fragment LDS byte offsets
    int off[5];
    #pragma unroll
    for (int i = 0; i < 5; ++i) {
        int tap = 2 * i + (g >> 1);
        if (tap > 8) tap = 8;                   // dead K (weights are 0)
        int kh = tap / 3;
        int kw = tap - kh * 3;
        int col = m + kw;
        int o = (kh * TC + col) * 32 + (g & 1) * 16;
        off[i] = o ^ ((col & 4) << 2);          // matches xt pre-swizzle
    }

#define STAGE(BUF, W0) do {                                                   \
        _Pragma("unroll")                                                     \
        for (int p = 0; p < 5; ++p) {                                         \
            if (p == 4 && !tail) break;                                       \
            int w = (W0) + swloc[p]; if (w > WIN - 1) w = WIN - 1;            \
            const unsigned* src = sbase[p] + (size_t)w * 8;                   \
            __builtin_amdgcn_global_load_lds(                                 \
                (const __attribute__((address_space(1))) unsigned*)src,      \
                (__attribute__((address_space(3))) unsigned*)(lds + (BUF) + sdst[p]), \
                16, 0, 0);                                                    \
        }                                                                     \
    } while (0)

#define COMPUTE(BUF, W0) do {                                                 \
        const char* ldsb = (const char*)(lds + (BUF));                        \
        _Pragma("unroll")                                                     \
        for (int hl4 = 0; hl4 < 4; ++hl4) {                                   \
            int hl = wv * 4 + hl4;                                            \
            _Pragma("unroll")                                                 \
            for (int nh = 0; nh < 2; ++nh) {                                  \
                int wl = nh * 16;                                             \
                int tb = (hl * TC + wl) * 32;                                 \
                f32x4 acc = {0.f, 0.f, 0.f, 0.f};                             \
                _Pragma("unroll")                                             \
                for (int i = 0; i < 5; ++i) {                                 \
                    bf16x8 a = *(const bf16x8*)(ldsb + (tb + off[i]));        \
                    acc = __builtin_amdgcn_mfma_f32_16x16x32_bf16(a, wf[i], acc, 0, 0, 0); \
                }                                                             \
                int w = (W0) + wl + g * 4;                                    \
                float* op = out + m * (size_t)PLANE_OUT                       \
                                + (size_t)(h0 + hl) * WOUT + w;               \
                if (w + 3 < WOUT) {                                           \
                    *(f32x4_u*)op = acc;                                      \
                } else {                                                      \
                    _Pragma("unroll")                                         \
                    for (int r = 0; r < 4; ++r)                               \
                        if (w + r < WOUT) op[r] = acc[r];                     \
                }                                                             \
            }                                                                 \
        }                                                                     \
    } while (0)

    // prologue
    STAGE(0, w0base);
    asm volatile("s_waitcnt vmcnt(0)" ::: "memory");
    __builtin_amdgcn_s_barrier();
    __builtin_amdgcn_sched_barrier(0);

    #pragma unroll
    for (int t = 0; t < STRIP; ++t) {
        const int buf  = (t & 1) * BUFU32;
        const int nbuf = ((t + 1) & 1) * BUFU32;
        if (t + 1 < STRIP) STAGE(nbuf, w0base + (t + 1) * 32);
        __builtin_amdgcn_sched_barrier(0);      // pin: stage loads issue first
        COMPUTE(buf, w0base + t * 32);
        // drain only the stage loads (oldest); leave stores in flight
        asm volatile("s_waitcnt vmcnt(8) lgkmcnt(0)" ::: "memory");
        __builtin_amdgcn_s_barrier();
        __builtin_amdgcn_sched_barrier(0);
    }
#undef STAGE
#undef COMPUTE
}

// ---------------- fallback: single-buffer conv (round-5 version) -------------
__global__ __launch_bounds__(512, 8)
void conv3x3_mfma2(const unsigned* __restrict__ xt,
                   const unsigned* __restrict__ wfbuf,
                   float* __restrict__ out) {
    __shared__ unsigned lds[NCHUNK * 4];

    const int tid  = threadIdx.x;
    const int lane = tid & 63;
    const int wv   = tid >> 6;
    const int m    = lane & 15;
    const int g    = lane >> 4;

    int bid = blockIdx.x;
    int swz = (bid & 7) * 512 + (bid >> 3);
    int h0 = (swz >> 6) * 32; if (h0 > HOUT - 32) h0 = HOUT - 32;
    int w0 = (swz & 63) * 32;

    {
        int base = wv * 64;
        #pragma unroll
        for (int pass = 0; pass < 4; ++pass) {
            int c   = pass * 512 + tid;
            int row = (c * 964) >> 16;
            int sub = c - row * 68;
            int w   = w0 + (sub >> 1); if (w > WIN - 1) w = WIN - 1;
            const unsigned* src = xt + ((h0 + row) * WIN + w) * 8 + (sub & 1) * 4;
            __builtin_amdgcn_global_load_lds(
                (const __attribute__((address_space(1))) unsigned*)src,
                (__attribute__((address_space(3))) unsigned*)&lds[(pass * 512 + base) * 4],
                16, 0, 0);
        }
        if (tid < 264) {
            int c   = 2048 + tid;
            int row = (c * 964) >> 16;
            int sub = c - row * 68;
            int w   = w0 + (sub >> 1); if (w > WIN - 1) w = WIN - 1;
            const unsigned* src = xt + ((h0 + row) * WIN + w) * 8 + (sub & 1) * 4;
            __builtin_amdgcn_global_load_lds(
                (const __attribute__((address_space(1))) unsigned*)src,
                (__attribute__((address_space(3))) unsigned*)&lds[(2048 + base) * 4],
                16, 0, 0);
        }
    }

    bf16x8 wf[5];
    #pragma unroll
    for (int i = 0; i < 5; ++i)
        wf[i] = *(const bf16x8*)(wfbuf + (i * 64 + lane) * 4);

    int off[5];
    #pragma unroll
    for (int i = 0; i < 5; ++i) {
        int tap = 2 * i + (g >> 1);
        if (tap > 8) tap = 8;
        int kh = tap / 3;
        int kw = tap - kh * 3;
        int col = m + kw;
        int o = (kh * TC + col) * 32 + (g & 1) * 16;
        off[i] = o ^ ((col & 4) << 2);
    }

    __syncthreads();

    const char* ldsb = (const char*)lds;

    #pragma unroll
    for (int hl4 = 0; hl4 < 4; ++hl4) {
        int hl = wv * 4 + hl4;
        int h  = h0 + hl;
        #pragma unroll
        for (int nh = 0; nh < 2; ++nh) {
            int wl = nh * 16;
            int tb = (hl * TC + wl) * 32;
            f32x4 acc = {0.f, 0.f, 0.f, 0.f};
            #pragma unroll
            for (int i = 0; i < 5; ++i) {
                bf16x8 a = *(const bf16x8*)(ldsb + (tb + off[i]));
                acc = __builtin_amdgcn_mfma_f32_16x16x32_bf16(a, wf[i], acc, 0, 0, 0);
            }
            int w = w0 + wl + g * 4;
            float* op = out + m * (size_t)PLANE_OUT + (size_t)h * WOUT + w;
            if (w + 3 < WOUT) {
                *(f32x4_u*)op = acc;
            } else {
                #pragma unroll
                for (int r = 0; r < 4; ++r)
                    if (w + r < WOUT) op[r] = acc[r];
            }
        }
    }
}

// ---------------- fallback (single-pass fp32 input), used if ws too small ----
__global__ __launch_bounds__(256, 4)
void conv3x3_mfma(const float* __restrict__ x,
                  const float* __restrict__ k,
                  float* __restrict__ out) {
    __shared__ short lds[TR * TC * 16];
    const int tid  = threadIdx.x;
    const int lane = tid & 63;
    const int wv   = tid >> 6;
    const int m    = lane & 15;
    const int g    = lane >> 4;
    int bid = blockIdx.x;
    int swz = (bid & 7) * 512 + (bid >> 3);
    int h0 = (swz >> 6) * 32;
    int w0 = (swz & 63) * 32;
    for (int p = tid; p < TR * TC; p += 256) {
        int r = p / TC, c = p - r * TC;
        int hh = h0 + r; if (hh > HIN - 1) hh = HIN - 1;
        int ww = w0 + c; if (ww > WIN - 1) ww = WIN - 1;
        const float* gp = x + hh * WIN + ww;
        short t[16];
        #pragma unroll
        for (int ci = 0; ci < 16; ++ci) t[ci] = f2bf(gp[ci * PLANE_IN]);
        bf16x8 lo, hi;
        #pragma unroll
        for (int j = 0; j < 8; ++j) { lo[j] = t[j]; hi[j] = t[8 + j]; }
        int sw = (c >> 2) & 1;
        bf16x8* dst = (bf16x8*)&lds[p * 16];
        dst[sw] = lo; dst[1 - sw] = hi;
    }
    bf16x8 wf[5];
    #pragma unroll
    for (int i = 0; i < 5; ++i)
        #pragma unroll
        for (int j = 0; j < 8; ++j) {
            int kk = 32 * i + 8 * g + j;
            int tap = kk >> 4, ci = kk & 15;
            short v = 0;
            if (tap < 9) v = f2bf(k[(m * 16 + ci) * 9 + tap]);
            wf[i][j] = v;
        }
    int off[5];
    #pragma unroll
    for (int i = 0; i < 5; ++i) {
        int tap = 2 * i + (g >> 1);
        if (tap > 8) tap = 8;
        int kh = tap / 3, kw = tap - kh * 3;
        int col = m + kw;
        int o = (kh * TC + col) * 32 + (g & 1) * 16;
        off[i] = o ^ ((col & 4) << 2);
    }
    __syncthreads();
    const char* ldsb = (const char*)lds;
    const int coBase = g * 4;
    for (int hl8 = 0; hl8 < 8; ++hl8) {
        int hl = wv * 8 + hl8;
        int h = h0 + hl;
        bool hok = (h < HOUT);
        #pragma unroll
        for (int nh = 0; nh < 2; ++nh) {
            int wl = nh * 16;
            int tb = (hl * TC + wl) * 32;
            f32x4 acc = {0.f, 0.f, 0.f, 0.f};
            #pragma unroll
            for (int i = 0; i < 5; ++i) {
                bf16x8 b = *(const bf16x8*)(ldsb + (tb + off[i]));
                acc = __builtin_amdgcn_mfma_f32_16x16x32_bf16(wf[i], b, acc, 0, 0, 0);
            }
            int w = w0 + wl + m;
            if (hok && w < WOUT) {
                float* op = out + h * WOUT + w;
                #pragma unroll
                for (int r = 0; r < 4; ++r)
                    op[(coBase + r) * PLANE_OUT] = acc[r];
            }
        }
    }
}

extern "C" void kernel_launch(void* const* d_in, const int* in_sizes, int n_in,
                              void* d_out, int out_size, void* d_ws, size_t ws_size,
                              hipStream_t stream) {
    const float* x = (const float*)d_in[0];
    const float* k = (const float*)d_in[1];
    float* out = (float*)d_out;
    const size_t need = (XT_U32 + WF_U32) * 4;
    if (ws_size >= need) {
        unsigned* xt = (unsigned*)d_ws;
        unsigned* wfbuf = xt + XT_U32;
        pack_bf16<<<dim3(8192), dim3(256), 0, stream>>>(x, k, xt, wfbuf);
        hipError_t e = hipFuncSetAttribute(
            reinterpret_cast<const void*>(conv3x3_strip),
            hipFuncAttributeMaxDynamicSharedMemorySize, 2 * NCHUNK * 16);
        if (e == hipSuccess) {
            conv3x3_strip<<<dim3(512), dim3(512), 2 * NCHUNK * 16, stream>>>(xt, wfbuf, out);
        } else {
            conv3x3_mfma2<<<dim3(4096), dim3(512), 0, stream>>>(xt, wfbuf, out);
        }
    } else {
        conv3x3_mfma<<<dim3(4096), dim3(256), 0, stream>>>(x, k, out);
    }
}

// Round 7
// 156.571 us; speedup vs baseline: 1.6861x; 1.6861x over previous
//
#include <hip/hip_runtime.h>

// Fused single-pass 3x3 VALID conv via bf16 MFMA implicit GEMM.
// x:(16,2048,2048) fp32, k:(16,16,3,3) fp32 -> out:(16,2046,2046) fp32
// Per 32x32 output tile: stage 34x36x16ci as bf16 in LDS (fp32->bf16 packed
// in registers, ds_write_b128, XOR-swizzled), then 5x mfma_16x16x32_bf16 per
// 16x16 sub-tile (K = tap*16+ci padded 144->160; dead K has zero weights).
// Weight fragments precomputed once by a tiny setup kernel into d_ws.

#define HIN   2048
#define WIN   2048
#define HOUT  2046
#define WOUT  2046
#define PLANE_IN  (HIN * WIN)
#define PLANE_OUT (HOUT * WOUT)
#define TR 34
#define TC 36                          // padded staging stride (cols)
#define NTASK (TR * 18 * 2)            // 1224: 34 rows x 18 w-pairs x 2 ci-halves
#define WF_U32 (5 * 64 * 4)            // weight-frag buffer (5 KiB)

typedef __attribute__((ext_vector_type(8))) short bf16x8;
typedef __attribute__((ext_vector_type(4))) float f32x4;
typedef __attribute__((ext_vector_type(4))) unsigned u32x4;
typedef f32x4 __attribute__((aligned(4))) f32x4_u;

static __device__ __forceinline__ short f2bf(float f) {
    unsigned u = __float_as_uint(f);
    return (short)((u + 0x7FFFu + ((u >> 16) & 1u)) >> 16);   // RNE
}
static __device__ __forceinline__ unsigned pk2(float lo, float hi) {
    unsigned a = __float_as_uint(lo);
    unsigned b = __float_as_uint(hi);
    a = (a + 0x7FFFu + ((a >> 16) & 1u)) >> 16;
    b = (b + 0x7FFFu + ((b >> 16) & 1u)) & 0xFFFF0000u;
    return a | b;
}

// ---------------- setup: per-lane MFMA weight fragments ----------------------
__global__ __launch_bounds__(64)
void wf_setup(const float* __restrict__ k, unsigned* __restrict__ wfbuf) {
    int lane = threadIdx.x;
    int m = lane & 15, g = lane >> 4;
    #pragma unroll
    for (int i = 0; i < 5; ++i) {
        u32x4 q;
        #pragma unroll
        for (int jj = 0; jj < 4; ++jj) {
            unsigned r = 0;
            #pragma unroll
            for (int e = 0; e < 2; ++e) {
                int kk  = 32 * i + 8 * g + 2 * jj + e;
                int tap = kk >> 4;
                int ci  = kk & 15;
                unsigned v = 0;
                if (tap < 9) v = (unsigned short)f2bf(k[(m * 16 + ci) * 9 + tap]);
                r |= v << (16 * e);
            }
            q[jj] = r;
        }
        *(u32x4*)(wfbuf + (i * 64 + lane) * 4) = q;
    }
}

// ---------------- fused conv ----------------
__global__ __launch_bounds__(512, 6)
void conv3x3_fused(const float* __restrict__ x,
                   const unsigned* __restrict__ wfbuf,
                   float* __restrict__ out) {
    __shared__ unsigned lds[TR * TC * 8];   // 34*36*32B = 39168 B

    const int tid  = threadIdx.x;
    const int lane = tid & 63;
    const int wv   = tid >> 6;
    const int m    = lane & 15;
    const int g    = lane >> 4;

    int bid = blockIdx.x;                      // 4096 blocks (64 x 64 tiles)
    int swz = (bid & 7) * 512 + (bid >> 3);    // XCD-chunked (4096 % 8 == 0)
    int h0 = (swz >> 6) * 32; if (h0 > HOUT - 32) h0 = HOUT - 32;  // 2014
    int w0 = (swz & 63) * 32;

    // ---- stage: fp32 -> bf16 transpose into LDS [row][col][ci], swizzled ----
    #pragma unroll
    for (int p = 0; p < 3; ++p) {
        int t = p * 512 + tid;
        if (t < NTASK) {
            int wp  = t % 18;                   // w-pair within 36-col span
            int r2  = t / 18;
            int cih = r2 & 1;                   // ci-half
            int row = r2 >> 1;                  // 0..33
            int c   = 2 * wp;                   // local col (even)
            int w   = w0 + c; if (w > WIN - 2) w = WIN - 2;   // float2-safe clamp
            const float* gp = x + (size_t)(cih * 8) * PLANE_IN
                                + (size_t)(h0 + row) * WIN + w;
            float2 f0 = *(const float2*)(gp + 0 * PLANE_IN);
            float2 f1 = *(const float2*)(gp + 1 * PLANE_IN);
            float2 f2 = *(const float2*)(gp + 2 * PLANE_IN);
            float2 f3 = *(const float2*)(gp + 3 * PLANE_IN);
            float2 f4 = *(const float2*)(gp + 4 * PLANE_IN);
            float2 f5 = *(const float2*)(gp + 5 * PLANE_IN);
            float2 f6 = *(const float2*)(gp + 6 * PLANE_IN);
            float2 f7 = *(const float2*)(gp + 7 * PLANE_IN);
            u32x4 ch0, ch1;
            ch0[0] = pk2(f0.x, f1.x); ch0[1] = pk2(f2.x, f3.x);
            ch0[2] = pk2(f4.x, f5.x); ch0[3] = pk2(f6.x, f7.x);
            ch1[0] = pk2(f0.y, f1.y); ch1[1] = pk2(f2.y, f3.y);
            ch1[2] = pk2(f4.y, f5.y); ch1[3] = pk2(f6.y, f7.y);
            // chunk addr: [row][c][cihalf], XOR-swizzled on (c&4); c,c+1 share key
            int a = (((row * TC + c) * 32) + cih * 16) ^ ((c & 4) << 2);
            *(u32x4*)((char*)lds + a)      = ch0;   // col c
            *(u32x4*)((char*)lds + a + 32) = ch1;   // col c+1
        }
    }

    // ---- weight fragments: 5 coalesced 16B loads (overlap staging) ----
    bf16x8 wf[5];
    #pragma unroll
    for (int i = 0; i < 5; ++i)
        wf[i] = *(const bf16x8*)(wfbuf + (i * 64 + lane) * 4);

    // ---- per-lane A-fragment LDS byte offsets ----
    int off[5];
    #pragma unroll
    for (int i = 0; i < 5; ++i) {
        int tap = 2 * i + (g >> 1);
        if (tap > 8) tap = 8;                   // dead K (weights are 0)
        int kh = tap / 3;
        int kw = tap - kh * 3;
        int col = m + kw;
        int o = (kh * TC + col) * 32 + (g & 1) * 16;
        off[i] = o ^ ((col & 4) << 2);          // matches staging swizzle
    }

    __syncthreads();

    const char* ldsb = (const char*)lds;

    #pragma unroll
    for (int hl4 = 0; hl4 < 4; ++hl4) {
        int hl = wv * 4 + hl4;                  // h always < HOUT (h0 <= 2014)
        int h  = h0 + hl;
        #pragma unroll
        for (int nh = 0; nh < 2; ++nh) {
            int wl = nh * 16;
            int tb = (hl * TC + wl) * 32;
            f32x4 acc = {0.f, 0.f, 0.f, 0.f};
            #pragma unroll
            for (int i = 0; i < 5; ++i) {
                bf16x8 a = *(const bf16x8*)(ldsb + (tb + off[i]));
                acc = __builtin_amdgcn_mfma_f32_16x16x32_bf16(a, wf[i], acc, 0, 0, 0);
            }
            // D: row = g*4+r = spatial, col = m = co  ->  float4 store
            int w = w0 + wl + g * 4;
            float* op = out + m * (size_t)PLANE_OUT + (size_t)h * WOUT + w;
            if (w + 3 < WOUT) {
                *(f32x4_u*)op = acc;
            } else {
                #pragma unroll
                for (int r = 0; r < 4; ++r)
                    if (w + r < WOUT) op[r] = acc[r];
            }
        }
    }
}

// ---------------- fallback (no workspace): single-pass fp32 staging ----------
__global__ __launch_bounds__(256, 4)
void conv3x3_mfma(const float* __restrict__ x,
                  const float* __restrict__ k,
                  float* __restrict__ out) {
    __shared__ short lds[TR * 34 * 16];
    const int tid  = threadIdx.x;
    const int lane = tid & 63;
    const int wv   = tid >> 6;
    const int m    = lane & 15;
    const int g    = lane >> 4;
    int bid = blockIdx.x;
    int swz = (bid & 7) * 512 + (bid >> 3);
    int h0 = (swz >> 6) * 32;
    int w0 = (swz & 63) * 32;
    for (int p = tid; p < TR * 34; p += 256) {
        int r = p / 34, c = p - r * 34;
        int hh = h0 + r; if (hh > HIN - 1) hh = HIN - 1;
        int ww = w0 + c; if (ww > WIN - 1) ww = WIN - 1;
        const float* gp = x + hh * WIN + ww;
        short t[16];
        #pragma unroll
        for (int ci = 0; ci < 16; ++ci) t[ci] = f2bf(gp[ci * PLANE_IN]);
        bf16x8 lo, hi;
        #pragma unroll
        for (int j = 0; j < 8; ++j) { lo[j] = t[j]; hi[j] = t[8 + j]; }
        int sw = (c >> 2) & 1;
        bf16x8* dst = (bf16x8*)&lds[p * 16];
        dst[sw] = lo; dst[1 - sw] = hi;
    }
    bf16x8 wf[5];
    #pragma unroll
    for (int i = 0; i < 5; ++i)
        #pragma unroll
        for (int j = 0; j < 8; ++j) {
            int kk = 32 * i + 8 * g + j;
            int tap = kk >> 4, ci = kk & 15;
            short v = 0;
            if (tap < 9) v = f2bf(k[(m * 16 + ci) * 9 + tap]);
            wf[i][j] = v;
        }
    int off[5];
    #pragma unroll
    for (int i = 0; i < 5; ++i) {
        int tap = 2 * i + (g >> 1);
        if (tap > 8) tap = 8;
        int kh = tap / 3, kw = tap - kh * 3;
        int col = m + kw;
        int o = (kh * 34 + col) * 32 + (g & 1) * 16;
        off[i] = o ^ ((col & 4) << 2);
    }
    __syncthreads();
    const char* ldsb = (const char*)lds;
    const int coBase = g * 4;
    for (int hl8 = 0; hl8 < 8; ++hl8) {
        int hl = wv * 8 + hl8;
        int h = h0 + hl;
        bool hok = (h < HOUT);
        #pragma unroll
        for (int nh = 0; nh < 2; ++nh) {
            int wl = nh * 16;
            int tb = (hl * 34 + wl) * 32;
            f32x4 acc = {0.f, 0.f, 0.f, 0.f};
            #pragma unroll
            for (int i = 0; i < 5; ++i) {
                bf16x8 b = *(const bf16x8*)(ldsb + (tb + off[i]));
                acc = __builtin_amdgcn_mfma_f32_16x16x32_bf16(wf[i], b, acc, 0, 0, 0);
            }
            int w = w0 + wl + m;
            if (hok && w < WOUT) {
                float* op = out + h * WOUT + w;
                #pragma unroll
                for (int r = 0; r < 4; ++r)
                    op[(coBase + r) * PLANE_OUT] = acc[r];
            }
        }
    }
}

extern "C" void kernel_launch(void* const* d_in, const int* in_sizes, int n_in,
                              void* d_out, int out_size, void* d_ws, size_t ws_size,
                              hipStream_t stream) {
    const float* x = (const float*)d_in[0];
    const float* k = (const float*)d_in[1];
    float* out = (float*)d_out;
    if (ws_size >= WF_U32 * 4) {
        unsigned* wfbuf = (unsigned*)d_ws;
        wf_setup<<<dim3(1), dim3(64), 0, stream>>>(k, wfbuf);
        conv3x3_fused<<<dim3(4096), dim3(512), 0, stream>>>(x, wfbuf, out);
    } else {
        conv3x3_mfma<<<dim3(4096), dim3(256), 0, stream>>>(x, k, out);
    }
}

// Round 8
// 153.039 us; speedup vs baseline: 1.7250x; 1.0231x over previous
//
#include <hip/hip_runtime.h>

// Fused single-pass 3x3 VALID conv via bf16 MFMA implicit GEMM.
// x:(16,2048,2048) fp32, k:(16,16,3,3) fp32 -> out:(16,2046,2046) fp32
// Per 32x32 output tile: stage 34x36x16ci as bf16 in LDS via 612 quad-tasks
// (8x float4 loads in flight per task -> 16 pk2 -> 4 ds_write_b128,
// XOR-swizzled), then 5x mfma_16x16x32_bf16 per 16x16 sub-tile
// (K = tap*16+ci padded 144->160; dead K has zero weights).
// Weight fragments precomputed once by a tiny setup kernel into d_ws.

#define HIN   2048
#define WIN   2048
#define HOUT  2046
#define WOUT  2046
#define PLANE_IN  (HIN * WIN)
#define PLANE_OUT (HOUT * WOUT)
#define TR 34
#define TC 36                          // padded staging stride (cols)
#define NQTASK (TR * 9 * 2)            // 612: 34 rows x 9 w-quads x 2 ci-halves
#define WF_U32 (5 * 64 * 4)            // weight-frag buffer (5 KiB)

typedef __attribute__((ext_vector_type(8))) short bf16x8;
typedef __attribute__((ext_vector_type(4))) float f32x4;
typedef __attribute__((ext_vector_type(4))) unsigned u32x4;
typedef f32x4 __attribute__((aligned(4))) f32x4_u;

static __device__ __forceinline__ short f2bf(float f) {
    unsigned u = __float_as_uint(f);
    return (short)((u + 0x7FFFu + ((u >> 16) & 1u)) >> 16);   // RNE
}
static __device__ __forceinline__ unsigned pk2(float lo, float hi) {
    unsigned a = __float_as_uint(lo);
    unsigned b = __float_as_uint(hi);
    a = (a + 0x7FFFu + ((a >> 16) & 1u)) >> 16;
    b = (b + 0x7FFFu + ((b >> 16) & 1u)) & 0xFFFF0000u;
    return a | b;
}

// ---------------- setup: per-lane MFMA weight fragments ----------------------
__global__ __launch_bounds__(64)
void wf_setup(const float* __restrict__ k, unsigned* __restrict__ wfbuf) {
    int lane = threadIdx.x;
    int m = lane & 15, g = lane >> 4;
    #pragma unroll
    for (int i = 0; i < 5; ++i) {
        u32x4 q;
        #pragma unroll
        for (int jj = 0; jj < 4; ++jj) {
            unsigned r = 0;
            #pragma unroll
            for (int e = 0; e < 2; ++e) {
                int kk  = 32 * i + 8 * g + 2 * jj + e;
                int tap = kk >> 4;
                int ci  = kk & 15;
                unsigned v = 0;
                if (tap < 9) v = (unsigned short)f2bf(k[(m * 16 + ci) * 9 + tap]);
                r |= v << (16 * e);
            }
            q[jj] = r;
        }
        *(u32x4*)(wfbuf + (i * 64 + lane) * 4) = q;
    }
}

// ---------------- fused conv ----------------
__global__ __launch_bounds__(512, 6)
void conv3x3_fused(const float* __restrict__ x,
                   const unsigned* __restrict__ wfbuf,
                   float* __restrict__ out) {
    __shared__ unsigned lds[TR * TC * 8];   // 34*36*32B = 39168 B

    const int tid  = threadIdx.x;
    const int lane = tid & 63;
    const int wv   = tid >> 6;
    const int m    = lane & 15;
    const int g    = lane >> 4;

    int bid = blockIdx.x;                      // 4096 blocks (64 x 64 tiles)
    int swz = (bid & 7) * 512 + (bid >> 3);    // XCD-chunked (4096 % 8 == 0)
    int h0 = (swz >> 6) * 32; if (h0 > HOUT - 32) h0 = HOUT - 32;  // 2014
    int w0 = (swz & 63) * 32;

    // ---- stage: quad-tasks, 8 float4 loads in flight -> pack -> 4 ds_writes
#define STAGE_TASK(T) do {                                                    \
        int t   = (T);                                                        \
        int q   = t % 9;                                                      \
        int r2  = t / 9;                                                      \
        int cih = r2 & 1;                                                     \
        int row = r2 >> 1;                                                    \
        int c   = 4 * q;                                                      \
        int w   = w0 + c; if (w > WIN - 4) w = WIN - 4;                       \
        const float* gp = x + (size_t)(cih * 8) * PLANE_IN                    \
                            + (size_t)(h0 + row) * WIN + w;                   \
        float4 f0 = *(const float4*)(gp + 0 * (size_t)PLANE_IN);              \
        float4 f1 = *(const float4*)(gp + 1 * (size_t)PLANE_IN);              \
        float4 f2 = *(const float4*)(gp + 2 * (size_t)PLANE_IN);              \
        float4 f3 = *(const float4*)(gp + 3 * (size_t)PLANE_IN);              \
        float4 f4 = *(const float4*)(gp + 4 * (size_t)PLANE_IN);              \
        float4 f5 = *(const float4*)(gp + 5 * (size_t)PLANE_IN);              \
        float4 f6 = *(const float4*)(gp + 6 * (size_t)PLANE_IN);              \
        float4 f7 = *(const float4*)(gp + 7 * (size_t)PLANE_IN);              \
        int a = ((row * TC + c) * 32 + cih * 16) ^ ((c & 4) << 2);            \
        u32x4 ch;                                                             \
        ch[0] = pk2(f0.x, f1.x); ch[1] = pk2(f2.x, f3.x);                     \
        ch[2] = pk2(f4.x, f5.x); ch[3] = pk2(f6.x, f7.x);                     \
        *(u32x4*)((char*)lds + a)      = ch;                                  \
        ch[0] = pk2(f0.y, f1.y); ch[1] = pk2(f2.y, f3.y);                     \
        ch[2] = pk2(f4.y, f5.y); ch[3] = pk2(f6.y, f7.y);                     \
        *(u32x4*)((char*)lds + a + 32) = ch;                                  \
        ch[0] = pk2(f0.z, f1.z); ch[1] = pk2(f2.z, f3.z);                     \
        ch[2] = pk2(f4.z, f5.z); ch[3] = pk2(f6.z, f7.z);                     \
        *(u32x4*)((char*)lds + a + 64) = ch;                                  \
        ch[0] = pk2(f0.w, f1.w); ch[1] = pk2(f2.w, f3.w);                     \
        ch[2] = pk2(f4.w, f5.w); ch[3] = pk2(f6.w, f7.w);                     \
        *(u32x4*)((char*)lds + a + 96) = ch;                                  \
    } while (0)

    STAGE_TASK(tid);
    if (tid < NQTASK - 512) STAGE_TASK(512 + tid);
#undef STAGE_TASK

    // ---- weight fragments: 5 coalesced 16B loads (L2-hot) ----
    bf16x8 wf[5];
    #pragma unroll
    for (int i = 0; i < 5; ++i)
        wf[i] = *(const bf16x8*)(wfbuf + (i * 64 + lane) * 4);

    // ---- per-lane A-fragment LDS byte offsets ----
    int off[5];
    #pragma unroll
    for (int i = 0; i < 5; ++i) {
        int tap = 2 * i + (g >> 1);
        if (tap > 8) tap = 8;                   // dead K (weights are 0)
        int kh = tap / 3;
        int kw = tap - kh * 3;
        int col = m + kw;
        int o = (kh * TC + col) * 32 + (g & 1) * 16;
        off[i] = o ^ ((col & 4) << 2);          // matches staging swizzle
    }

    __syncthreads();

    const char* ldsb = (const char*)lds;

    #pragma unroll
    for (int hl4 = 0; hl4 < 4; ++hl4) {
        int hl = wv * 4 + hl4;                  // h always < HOUT (h0 <= 2014)
        int h  = h0 + hl;
        #pragma unroll
        for (int nh = 0; nh < 2; ++nh) {
            int wl = nh * 16;
            int tb = (hl * TC + wl) * 32;
            f32x4 acc = {0.f, 0.f, 0.f, 0.f};
            #pragma unroll
            for (int i = 0; i < 5; ++i) {
                bf16x8 a = *(const bf16x8*)(ldsb + (tb + off[i]));
                acc = __builtin_amdgcn_mfma_f32_16x16x32_bf16(a, wf[i], acc, 0, 0, 0);
            }
            // D: row = g*4+r = spatial, col = m = co  ->  float4 store
            int w = w0 + wl + g * 4;
            float* op = out + m * (size_t)PLANE_OUT + (size_t)h * WOUT + w;
            if (w + 3 < WOUT) {
                *(f32x4_u*)op = acc;
            } else {
                #pragma unroll
                for (int r = 0; r < 4; ++r)
                    if (w + r < WOUT) op[r] = acc[r];
            }
        }
    }
}

// ---------------- fallback (no workspace): single-pass fp32 staging ----------
__global__ __launch_bounds__(256, 4)
void conv3x3_mfma(const float* __restrict__ x,
                  const float* __restrict__ k,
                  float* __restrict__ out) {
    __shared__ short lds[TR * 34 * 16];
    const int tid  = threadIdx.x;
    const int lane = tid & 63;
    const int wv   = tid >> 6;
    const int m    = lane & 15;
    const int g    = lane >> 4;
    int bid = blockIdx.x;
    int swz = (bid & 7) * 512 + (bid >> 3);
    int h0 = (swz >> 6) * 32;
    int w0 = (swz & 63) * 32;
    for (int p = tid; p < TR * 34; p += 256) {
        int r = p / 34, c = p - r * 34;
        int hh = h0 + r; if (hh > HIN - 1) hh = HIN - 1;
        int ww = w0 + c; if (ww > WIN - 1) ww = WIN - 1;
        const float* gp = x + hh * WIN + ww;
        short t[16];
        #pragma unroll
        for (int ci = 0; ci < 16; ++ci) t[ci] = f2bf(gp[ci * PLANE_IN]);
        bf16x8 lo, hi;
        #pragma unroll
        for (int j = 0; j < 8; ++j) { lo[j] = t[j]; hi[j] = t[8 + j]; }
        int sw = (c >> 2) & 1;
        bf16x8* dst = (bf16x8*)&lds[p * 16];
        dst[sw] = lo; dst[1 - sw] = hi;
    }
    bf16x8 wf[5];
    #pragma unroll
    for (int i = 0; i < 5; ++i)
        #pragma unroll
        for (int j = 0; j < 8; ++j) {
            int kk = 32 * i + 8 * g + j;
            int tap = kk >> 4, ci = kk & 15;
            short v = 0;
            if (tap < 9) v = f2bf(k[(m * 16 + ci) * 9 + tap]);
            wf[i][j] = v;
        }
    int off[5];
    #pragma unroll
    for (int i = 0; i < 5; ++i) {
        int tap = 2 * i + (g >> 1);
        if (tap > 8) tap = 8;
        int kh = tap / 3, kw = tap - kh * 3;
        int col = m + kw;
        int o = (kh * 34 + col) * 32 + (g & 1) * 16;
        off[i] = o ^ ((col & 4) << 2);
    }
    __syncthreads();
    const char* ldsb = (const char*)lds;
    const int coBase = g * 4;
    for (int hl8 = 0; hl8 < 8; ++hl8) {
        int hl = wv * 8 + hl8;
        int h = h0 + hl;
        bool hok = (h < HOUT);
        #pragma unroll
        for (int nh = 0; nh < 2; ++nh) {
            int wl = nh * 16;
            int tb = (hl * 34 + wl) * 32;
            f32x4 acc = {0.f, 0.f, 0.f, 0.f};
            #pragma unroll
            for (int i = 0; i < 5; ++i) {
                bf16x8 b = *(const bf16x8*)(ldsb + (tb + off[i]));
                acc = __builtin_amdgcn_mfma_f32_16x16x32_bf16(wf[i], b, acc, 0, 0, 0);
            }
            int w = w0 + wl + m;
            if (hok && w < WOUT) {
                float* op = out + h * WOUT + w;
                #pragma unroll
                for (int r = 0; r < 4; ++r)
                    op[(coBase + r) * PLANE_OUT] = acc[r];
            }
        }
    }
}

extern "C" void kernel_launch(void* const* d_in, const int* in_sizes, int n_in,
                              void* d_out, int out_size, void* d_ws, size_t ws_size,
                              hipStream_t stream) {
    const float* x = (const float*)d_in[0];
    const float* k = (const float*)d_in[1];
    float* out = (float*)d_out;
    if (ws_size >= WF_U32 * 4) {
        unsigned* wfbuf = (unsigned*)d_ws;
        wf_setup<<<dim3(1), dim3(64), 0, stream>>>(k, wfbuf);
        conv3x3_fused<<<dim3(4096), dim3(512), 0, stream>>>(x, wfbuf, out);
    } else {
        conv3x3_mfma<<<dim3(4096), dim3(256), 0, stream>>>(x, k, out);
    }
}

// Round 9
// 152.415 us; speedup vs baseline: 1.7320x; 1.0041x over previous
//
#include <hip/hip_runtime.h>

// Fused single-pass 3x3 VALID conv via bf16 MFMA implicit GEMM.
// x:(16,2048,2048) fp32, k:(16,16,3,3) fp32 -> out:(16,2046,2046) fp32
// Per 32x32 output tile: stage 34x36x16ci as bf16 in LDS via 612 quad-tasks.
// Each task: 8 float4 loads forced co-live (keep-alive asm) -> 16 pk2 ->
// 4 ds_write_b128 (XOR-swizzled), then 5x mfma_16x16x32_bf16 per 16x16
// sub-tile (K = tap*16+ci padded 144->160; dead K has zero weights).
// Weight fragments precomputed once by a tiny setup kernel into d_ws.

#define HIN   2048
#define WIN   2048
#define HOUT  2046
#define WOUT  2046
#define PLANE_IN  (HIN * WIN)
#define PLANE_OUT (HOUT * WOUT)
#define TR 34
#define TC 36                          // padded staging stride (cols)
#define NQTASK (TR * 9 * 2)            // 612: 34 rows x 9 w-quads x 2 ci-halves
#define WF_U32 (5 * 64 * 4)            // weight-frag buffer (5 KiB)

typedef __attribute__((ext_vector_type(8))) short bf16x8;
typedef __attribute__((ext_vector_type(4))) float f32x4;
typedef __attribute__((ext_vector_type(4))) unsigned u32x4;
typedef f32x4 __attribute__((aligned(4))) f32x4_u;

static __device__ __forceinline__ short f2bf(float f) {
    unsigned u = __float_as_uint(f);
    return (short)((u + 0x7FFFu + ((u >> 16) & 1u)) >> 16);   // RNE
}
static __device__ __forceinline__ unsigned pk2(float lo, float hi) {
    unsigned a = __float_as_uint(lo);
    unsigned b = __float_as_uint(hi);
    a = (a + 0x7FFFu + ((a >> 16) & 1u)) >> 16;
    b = (b + 0x7FFFu + ((b >> 16) & 1u)) & 0xFFFF0000u;
    return a | b;
}

// ---------------- setup: per-lane MFMA weight fragments ----------------------
__global__ __launch_bounds__(64)
void wf_setup(const float* __restrict__ k, unsigned* __restrict__ wfbuf) {
    int lane = threadIdx.x;
    int m = lane & 15, g = lane >> 4;
    #pragma unroll
    for (int i = 0; i < 5; ++i) {
        u32x4 q;
        #pragma unroll
        for (int jj = 0; jj < 4; ++jj) {
            unsigned r = 0;
            #pragma unroll
            for (int e = 0; e < 2; ++e) {
                int kk  = 32 * i + 8 * g + 2 * jj + e;
                int tap = kk >> 4;
                int ci  = kk & 15;
                unsigned v = 0;
                if (tap < 9) v = (unsigned short)f2bf(k[(m * 16 + ci) * 9 + tap]);
                r |= v << (16 * e);
            }
            q[jj] = r;
        }
        *(u32x4*)(wfbuf + (i * 64 + lane) * 4) = q;
    }
}

// ---------------- fused conv ----------------
__global__ __launch_bounds__(512, 8)
void conv3x3_fused(const float* __restrict__ x,
                   const unsigned* __restrict__ wfbuf,
                   float* __restrict__ out) {
    __shared__ unsigned lds[TR * TC * 8];   // 34*36*32B = 39168 B

    const int tid  = threadIdx.x;
    const int lane = tid & 63;
    const int wv   = tid >> 6;
    const int m    = lane & 15;
    const int g    = lane >> 4;

    int bid = blockIdx.x;                      // 4096 blocks (64 x 64 tiles)
    int swz = (bid & 7) * 512 + (bid >> 3);    // XCD-chunked (4096 % 8 == 0)
    int h0 = (swz >> 6) * 32; if (h0 > HOUT - 32) h0 = HOUT - 32;  // 2014
    int w0 = (swz & 63) * 32;

    // ---- stage: quad-tasks; 8 loads forced co-live, then pack, then ds_write
#define STAGE_TASK(T) do {                                                    \
        int t   = (T);                                                        \
        int q   = t % 9;                                                      \
        int r2  = t / 9;                                                      \
        int cih = r2 & 1;                                                     \
        int row = r2 >> 1;                                                    \
        int c   = 4 * q;                                                      \
        int w   = w0 + c; if (w > WIN - 4) w = WIN - 4;                       \
        const float* gp = x + (size_t)(cih * 8) * PLANE_IN                    \
                            + (size_t)(h0 + row) * WIN + w;                   \
        f32x4 f0 = *(const f32x4*)(gp + 0 * (size_t)PLANE_IN);                \
        f32x4 f1 = *(const f32x4*)(gp + 1 * (size_t)PLANE_IN);                \
        f32x4 f2 = *(const f32x4*)(gp + 2 * (size_t)PLANE_IN);                \
        f32x4 f3 = *(const f32x4*)(gp + 3 * (size_t)PLANE_IN);                \
        f32x4 f4 = *(const f32x4*)(gp + 4 * (size_t)PLANE_IN);                \
        f32x4 f5 = *(const f32x4*)(gp + 5 * (size_t)PLANE_IN);                \
        f32x4 f6 = *(const f32x4*)(gp + 6 * (size_t)PLANE_IN);                \
        f32x4 f7 = *(const f32x4*)(gp + 7 * (size_t)PLANE_IN);                \
        /* force all 8 loads in flight before any pack (liveness pin) */      \
        asm volatile("" :: "v"(f0), "v"(f1), "v"(f2), "v"(f3),                \
                           "v"(f4), "v"(f5), "v"(f6), "v"(f7));               \
        int a = ((row * TC + c) * 32 + cih * 16) ^ ((c & 4) << 2);            \
        u32x4 ch;                                                             \
        ch[0] = pk2(f0[0], f1[0]); ch[1] = pk2(f2[0], f3[0]);                 \
        ch[2] = pk2(f4[0], f5[0]); ch[3] = pk2(f6[0], f7[0]);                 \
        *(u32x4*)((char*)lds + a)      = ch;                                  \
        ch[0] = pk2(f0[1], f1[1]); ch[1] = pk2(f2[1], f3[1]);                 \
        ch[2] = pk2(f4[1], f5[1]); ch[3] = pk2(f6[1], f7[1]);                 \
        *(u32x4*)((char*)lds + a + 32) = ch;                                  \
        ch[0] = pk2(f0[2], f1[2]); ch[1] = pk2(f2[2], f3[2]);                 \
        ch[2] = pk2(f4[2], f5[2]); ch[3] = pk2(f6[2], f7[2]);                 \
        *(u32x4*)((char*)lds + a + 64) = ch;                                  \
        ch[0] = pk2(f0[3], f1[3]); ch[1] = pk2(f2[3], f3[3]);                 \
        ch[2] = pk2(f4[3], f5[3]); ch[3] = pk2(f6[3], f7[3]);                 \
        *(u32x4*)((char*)lds + a + 96) = ch;                                  \
    } while (0)

    STAGE_TASK(tid);
    if (tid < NQTASK - 512) STAGE_TASK(512 + tid);
#undef STAGE_TASK

    // ---- weight fragments: 5 coalesced 16B loads (L2-hot) ----
    bf16x8 wf[5];
    #pragma unroll
    for (int i = 0; i < 5; ++i)
        wf[i] = *(const bf16x8*)(wfbuf + (i * 64 + lane) * 4);

    // ---- per-lane A-fragment LDS byte offsets ----
    int off[5];
    #pragma unroll
    for (int i = 0; i < 5; ++i) {
        int tap = 2 * i + (g >> 1);
        if (tap > 8) tap = 8;                   // dead K (weights are 0)
        int kh = tap / 3;
        int kw = tap - kh * 3;
        int col = m + kw;
        int o = (kh * TC + col) * 32 + (g & 1) * 16;
        off[i] = o ^ ((col & 4) << 2);          // matches staging swizzle
    }

    __syncthreads();

    const char* ldsb = (const char*)lds;

    #pragma unroll
    for (int hl4 = 0; hl4 < 4; ++hl4) {
        int hl = wv * 4 + hl4;                  // h always < HOUT (h0 <= 2014)
        int h  = h0 + hl;
        #pragma unroll
        for (int nh = 0; nh < 2; ++nh) {
            int wl = nh * 16;
            int tb = (hl * TC + wl) * 32;
            f32x4 acc = {0.f, 0.f, 0.f, 0.f};
            #pragma unroll
            for (int i = 0; i < 5; ++i) {
                bf16x8 a = *(const bf16x8*)(ldsb + (tb + off[i]));
                acc = __builtin_amdgcn_mfma_f32_16x16x32_bf16(a, wf[i], acc, 0, 0, 0);
            }
            // D: row = g*4+r = spatial, col = m = co  ->  float4 store
            int w = w0 + wl + g * 4;
            float* op = out + m * (size_t)PLANE_OUT + (size_t)h * WOUT + w;
            if (w + 3 < WOUT) {
                *(f32x4_u*)op = acc;
            } else {
                #pragma unroll
                for (int r = 0; r < 4; ++r)
                    if (w + r < WOUT) op[r] = acc[r];
            }
        }
    }
}

// ---------------- fallback (no workspace): single-pass fp32 staging ----------
__global__ __launch_bounds__(256, 4)
void conv3x3_mfma(const float* __restrict__ x,
                  const float* __restrict__ k,
                  float* __restrict__ out) {
    __shared__ short lds[TR * 34 * 16];
    const int tid  = threadIdx.x;
    const int lane = tid & 63;
    const int wv   = tid >> 6;
    const int m    = lane & 15;
    const int g    = lane >> 4;
    int bid = blockIdx.x;
    int swz = (bid & 7) * 512 + (bid >> 3);
    int h0 = (swz >> 6) * 32;
    int w0 = (swz & 63) * 32;
    for (int p = tid; p < TR * 34; p += 256) {
        int r = p / 34, c = p - r * 34;
        int hh = h0 + r; if (hh > HIN - 1) hh = HIN - 1;
        int ww = w0 + c; if (ww > WIN - 1) ww = WIN - 1;
        const float* gp = x + hh * WIN + ww;
        short t[16];
        #pragma unroll
        for (int ci = 0; ci < 16; ++ci) t[ci] = f2bf(gp[ci * PLANE_IN]);
        bf16x8 lo, hi;
        #pragma unroll
        for (int j = 0; j < 8; ++j) { lo[j] = t[j]; hi[j] = t[8 + j]; }
        int sw = (c >> 2) & 1;
        bf16x8* dst = (bf16x8*)&lds[p * 16];
        dst[sw] = lo; dst[1 - sw] = hi;
    }
    bf16x8 wf[5];
    #pragma unroll
    for (int i = 0; i < 5; ++i)
        #pragma unroll
        for (int j = 0; j < 8; ++j) {
            int kk = 32 * i + 8 * g + j;
            int tap = kk >> 4, ci = kk & 15;
            short v = 0;
            if (tap < 9) v = f2bf(k[(m * 16 + ci) * 9 + tap]);
            wf[i][j] = v;
        }
    int off[5];
    #pragma unroll
    for (int i = 0; i < 5; ++i) {
        int tap = 2 * i + (g >> 1);
        if (tap > 8) tap = 8;
        int kh = tap / 3, kw = tap - kh * 3;
        int col = m + kw;
        int o = (kh * 34 + col) * 32 + (g & 1) * 16;
        off[i] = o ^ ((col & 4) << 2);
    }
    __syncthreads();
    const char* ldsb = (const char*)lds;
    const int coBase = g * 4;
    for (int hl8 = 0; hl8 < 8; ++hl8) {
        int hl = wv * 8 + hl8;
        int h = h0 + hl;
        bool hok = (h < HOUT);
        #pragma unroll
        for (int nh = 0; nh < 2; ++nh) {
            int wl = nh * 16;
            int tb = (hl * 34 + wl) * 32;
            f32x4 acc = {0.f, 0.f, 0.f, 0.f};
            #pragma unroll
            for (int i = 0; i < 5; ++i) {
                bf16x8 b = *(const bf16x8*)(ldsb + (tb + off[i]));
                acc = __builtin_amdgcn_mfma_f32_16x16x32_bf16(wf[i], b, acc, 0, 0, 0);
            }
            int w = w0 + wl + m;
            if (hok && w < WOUT) {
                float* op = out + h * WOUT + w;
                #pragma unroll
                for (int r = 0; r < 4; ++r)
                    op[(coBase + r) * PLANE_OUT] = acc[r];
            }
        }
    }
}

extern "C" void kernel_launch(void* const* d_in, const int* in_sizes, int n_in,
                              void* d_out, int out_size, void* d_ws, size_t ws_size,
                              hipStream_t stream) {
    const float* x = (const float*)d_in[0];
    const float* k = (const float*)d_in[1];
    float* out = (float*)d_out;
    if (ws_size >= WF_U32 * 4) {
        unsigned* wfbuf = (unsigned*)d_ws;
        wf_setup<<<dim3(1), dim3(64), 0, stream>>>(k, wfbuf);
        conv3x3_fused<<<dim3(4096), dim3(512), 0, stream>>>(x, wfbuf, out);
    } else {
        conv3x3_mfma<<<dim3(4096), dim3(256), 0, stream>>>(x, k, out);
    }
}